// Round 3
// baseline (178.863 us; speedup 1.0000x reference)
//
#include <hip/hip_runtime.h>
#include <math.h>

#define HDIM 256
#define PDIM 256
#define BATCH 8
#define LSEQ 4096
#define MTOT (BATCH * LSEQ)   // 32768
#define NCHUNK 128
#define CHLEN 32              // NCHUNK*CHLEN == LSEQ

typedef __attribute__((ext_vector_type(8))) short bf16x8;   // 8 bf16 = 4 VGPRs
typedef __attribute__((ext_vector_type(4))) float f32x4;

__device__ __forceinline__ unsigned short f2bf(float f) {
    union { float f; unsigned int u; } v; v.f = f;
    unsigned int r = v.u + 0x7FFFu + ((v.u >> 16) & 1u);   // RNE
    return (unsigned short)(r >> 16);
}
__device__ __forceinline__ float bf2f(unsigned int lo16) {
    union { unsigned int u; float f; } v; v.u = lo16 << 16;
    return v.f;
}

// async global->LDS, 16B per lane; LDS dest is wave-uniform base + lane*16
__device__ __forceinline__ void gload_lds16(const void* g, void* l) {
    __builtin_amdgcn_global_load_lds(
        (const __attribute__((address_space(1))) void*)g,
        (__attribute__((address_space(3))) void*)l, 16, 0, 0);
}

// ---------------- merged setup: par + W1t + W2t in one launch ----------------
// par floats: [0:512) a  [512:1024) coef  [1024:1536) a^CHLEN  (interleaved r,i)
// W1t[n][k]: n=2p -> Re(coef_p * B_tilde[p][k]); n=2p+1 -> Im. (bf16, [512][256])
// W2t[h][2p] = Cr[h][p]; W2t[h][2p+1] = -Ci[h][p]. (bf16, [256][512])
__global__ void wpack_k(const float* __restrict__ llr, const float* __restrict__ lim,
                        const float* __restrict__ ldl,
                        const float* __restrict__ Br, const float* __restrict__ Bi,
                        const float* __restrict__ Cr, const float* __restrict__ Ci,
                        unsigned short* __restrict__ W1t, unsigned short* __restrict__ W2t,
                        float* __restrict__ par) {
    int h = threadIdx.x;
    if (blockIdx.x < PDIM) {
        int p = blockIdx.x;
        float er = expf(llr[p]);
        float im = lim[p];
        float d  = expf(ldl[p]);
        float zr = -er * d, zi = im * d;
        float ea = expf(zr);
        float sz, cz; sincosf(zi, &sz, &cz);
        float ar = ea * cz, ai = ea * sz;
        float dr = -er, di = im;
        float den = dr * dr + di * di;
        float nr = ar - 1.0f, ni = ai;
        float cr = (nr * dr + ni * di) / den;
        float ci = (ni * dr - nr * di) / den;
        float br = Br[p * HDIM + h], bi = Bi[p * HDIM + h];
        W1t[(2 * p) * HDIM + h]     = f2bf(cr * br - ci * bi);
        W1t[(2 * p + 1) * HDIM + h] = f2bf(cr * bi + ci * br);
    } else if (blockIdx.x < 2 * PDIM) {
        int p = blockIdx.x - PDIM;
        W2t[h * (2 * PDIM) + 2 * p]     = f2bf(Cr[h * PDIM + p]);
        W2t[h * (2 * PDIM) + 2 * p + 1] = f2bf(-Ci[h * PDIM + p]);
    } else {
        int p = h;
        float er = expf(llr[p]);
        float im = lim[p];
        float d  = expf(ldl[p]);
        float zr = -er * d, zi = im * d;
        float ea = expf(zr);
        float sz, cz; sincosf(zi, &sz, &cz);
        float ar = ea * cz, ai = ea * sz;
        float dr = -er, di = im;
        float den = dr * dr + di * di;
        float nr = ar - 1.0f, ni = ai;
        float cr = (nr * dr + ni * di) / den;
        float ci = (ni * dr - nr * di) / den;
        float eC = expf((float)CHLEN * zr);
        float sC, cC;
        sincosf((float)CHLEN * zi, &sC, &cC);
        par[2 * p]            = ar;
        par[2 * p + 1]        = ai;
        par[512 + 2 * p]      = cr;
        par[512 + 2 * p + 1]  = ci;
        par[1024 + 2 * p]     = eC * cC;
        par[1024 + 2 * p + 1] = eC * sC;
    }
}

// ---------------- fused LayerNorm + GEMM1 ----------------
// Bu[32768][512] = LN(u)[32768][256] @ W1t^T, per-block 128x128 tile.
// LN computed in-block; A-tile lives in a resident 64KB LDS buffer, bf16,
// XOR chunk-swizzle (16B chunk index ^= row&7) on BOTH write and read side.
// Bs (W1t) staged per k-step via global_load_lds with the rule-#21 involution.
// The 4 bn-siblings re-read the same u panel -> same-XCD L2 hits via remap.
__launch_bounds__(256, 2)
__global__ void ln_gemm1_k(const float* __restrict__ u, const unsigned short* __restrict__ W1t,
                           unsigned short* __restrict__ Bu,
                           const float* __restrict__ gamma, const float* __restrict__ beta) {
    __shared__ __align__(16) unsigned short As[128 * 256];    // 64 KB, swizzled
    __shared__ __align__(16) unsigned short Bs[2][128 * 32];  // 16 KB
    const int t = threadIdx.x;
    const int lane = t & 63, w = t >> 6;

    // XCD remap (grid (4,256)): consecutive tiles (bn-siblings) on one XCD
    const int nbn  = (int)gridDim.x;
    const int flat = (int)blockIdx.y * nbn + (int)blockIdx.x;
    const int nwg  = nbn * (int)gridDim.y;
    const int tile = (flat & 7) * (nwg >> 3) + (flat >> 3);
    const int bn = tile % nbn, bm = tile / nbn;

    // Bs staging addresses (round-2 involution): wave w stages rows 32w..32w+31
    const int srow   = 32 * w + (lane >> 2);
    const int schunk = (lane & 3) ^ ((lane >> 3) & 3);
    const unsigned short* gB = W1t + (size_t)(bn * 128 + srow) * HDIM + schunk * 8;
    const int bl0 = (32 * w) * 32;
    const int bl1 = (32 * w + 16) * 32;

    // issue tile-0 B staging early: latency hides under the LN phase
    gload_lds16(gB,             &Bs[0][bl0]);
    gload_lds16(gB + 16 * HDIM, &Bs[0][bl1]);

    // ---------- LN phase: 4 rows per iteration (one row per wave) ----------
    const float4 g4 = *(const float4*)(gamma + lane * 4);
    const float4 b4 = *(const float4*)(beta + lane * 4);
    #pragma unroll 4
    for (int i = 0; i < 32; i++) {
        const int row = i * 4 + w;
        const float4 v = *(const float4*)(u + (size_t)(bm * 128 + row) * HDIM + lane * 4);
        float s  = v.x + v.y + v.z + v.w;
        float sq = v.x * v.x + v.y * v.y + v.z * v.z + v.w * v.w;
        #pragma unroll
        for (int o = 1; o < 64; o <<= 1) { s += __shfl_xor(s, o); sq += __shfl_xor(sq, o); }
        const float mu = s * (1.0f / HDIM);
        const float rs = rsqrtf(sq * (1.0f / HDIM) - mu * mu + 1e-5f);
        ushort4 o4;
        o4.x = f2bf((v.x - mu) * rs * g4.x + b4.x);
        o4.y = f2bf((v.y - mu) * rs * g4.y + b4.y);
        o4.z = f2bf((v.z - mu) * rs * g4.z + b4.z);
        o4.w = f2bf((v.w - mu) * rs * g4.w + b4.w);
        // swizzled write: chunk = lane>>1 (16B), chunk ^= row&7, half = lane&1
        const int idx = row * 256 + ((((lane >> 1) ^ (row & 7)) << 3) + (lane & 1) * 4);
        *(ushort4*)&As[idx] = o4;
    }

    // ---------- GEMM phase ----------
    const int wm = (w & 1) * 64, wn = (w >> 1) * 64;
    const int mrow = lane & 15;
    const int rsw  = (mrow >> 1) & 3;
    const int cch  = lane >> 4;
    const int fcol = (cch ^ rsw) * 8;          // Bs read slot (involution)

    f32x4 acc[4][4] = {};
    constexpr int NT = HDIM / 32;              // 8

    __syncthreads();                           // As complete + Bs tile0 landed

    #pragma unroll
    for (int tt = 0; tt < NT; ++tt) {
        const int cur = tt & 1;
        if (tt + 1 < NT) {
            const int k0 = (tt + 1) * 32;
            gload_lds16(gB + k0,             &Bs[cur ^ 1][bl0]);
            gload_lds16(gB + 16 * HDIM + k0, &Bs[cur ^ 1][bl1]);
        }
        const int cb = tt * 4;                 // 16B-chunk base = k0>>3
        bf16x8 fa[4], fb[4];
        #pragma unroll
        for (int i = 0; i < 4; i++) {
            const int r = wm + i * 16 + mrow;
            fa[i] = *(const bf16x8*)&As[r * 256 + (((cb + cch) ^ (r & 7)) << 3)];
            fb[i] = *(const bf16x8*)&Bs[cur][(wn + i * 16 + mrow) * 32 + fcol];
        }
        #pragma unroll
        for (int i = 0; i < 4; i++)
            #pragma unroll
            for (int j = 0; j < 4; j++)
                acc[i][j] = __builtin_amdgcn_mfma_f32_16x16x32_bf16(fa[i], fb[j], acc[i][j], 0, 0, 0);
        __syncthreads();
    }

    // epilogue: bf16 store to Bu. C/D layout: col = lane&15, row = (lane>>4)*4 + reg
    const int r0 = (lane >> 4) * 4, c0 = lane & 15;
    #pragma unroll
    for (int i = 0; i < 4; i++) {
        #pragma unroll
        for (int r = 0; r < 4; r++) {
            const size_t rowoff = (size_t)(bm * 128 + wm + i * 16 + r0 + r) * 512;
            #pragma unroll
            for (int j = 0; j < 4; j++)
                Bu[rowoff + bn * 128 + wn + j * 16 + c0] = f2bf(acc[i][j][r]);
        }
    }
}

// ---------------- chunked diagonal complex scan (pass 1+2 unchanged) ----------------
__global__ void scan_reduce_k(const unsigned short* __restrict__ Bu,
                              const float* __restrict__ par, float* __restrict__ last) {
    int t = threadIdx.x;
    int lane = t & 63, g = t >> 6;
    int c = blockIdx.x * 4 + g, b = blockIdx.y;
    int p0 = lane * 4;
    float4 a01 = *(const float4*)(par + 2 * p0);       // ar0 ai0 ar1 ai1
    float4 a23 = *(const float4*)(par + 2 * p0 + 4);   // ar2 ai2 ar3 ai3
    float ar[4] = {a01.x, a01.z, a23.x, a23.z};
    float ai[4] = {a01.y, a01.w, a23.y, a23.w};
    float xr[4] = {0.f, 0.f, 0.f, 0.f}, xi[4] = {0.f, 0.f, 0.f, 0.f};
    const uint4* q = (const uint4*)(Bu + ((size_t)b * LSEQ + (size_t)c * CHLEN) * 512) + lane;
    #pragma unroll 8
    for (int j = 0; j < CHLEN; j++) {
        uint4 v = q[(size_t)j * 64];   // row stride 512 bf16 = 64 uint4
        unsigned int vv[4] = {v.x, v.y, v.z, v.w};
        #pragma unroll
        for (int k = 0; k < 4; k++) {
            float vr = bf2f(vv[k] & 0xFFFFu), vi = bf2f(vv[k] >> 16);
            float nr = fmaf(ar[k], xr[k], fmaf(-ai[k], xi[k], vr));
            float ni = fmaf(ar[k], xi[k], fmaf(ai[k], xr[k], vi));
            xr[k] = nr; xi[k] = ni;
        }
    }
    float* lp = last + ((size_t)b * NCHUNK + c) * 512 + 2 * p0;
    *(float4*)lp       = make_float4(xr[0], xi[0], xr[1], xi[1]);
    *(float4*)(lp + 4) = make_float4(xr[2], xi[2], xr[3], xi[3]);
}

__global__ void scan_carry_k(const float* __restrict__ last, float* __restrict__ prefix,
                             const float* __restrict__ par) {
    int p = threadIdx.x, b = blockIdx.x;
    float Ar = par[1024 + 2 * p], Ai = par[1024 + 2 * p + 1];  // a^CHLEN
    float Pr = 0.0f, Pi = 0.0f;
    const float2* lp = (const float2*)(last + (size_t)b * NCHUNK * 512) + p;
    float2* pp = (float2*)(prefix + (size_t)b * NCHUNK * 512) + p;
    for (int c0 = 0; c0 < NCHUNK; c0 += 16) {
        float2 v[16];
        #pragma unroll
        for (int j = 0; j < 16; j++) v[j] = lp[(size_t)(c0 + j) * 256];
        #pragma unroll
        for (int j = 0; j < 16; j++) {
            pp[(size_t)(c0 + j) * 256] = make_float2(Pr, Pi);
            float nr = fmaf(Ar, Pr, fmaf(-Ai, Pi, v[j].x));
            float ni = fmaf(Ar, Pi, fmaf(Ai, Pr, v[j].y));
            Pr = nr; Pi = ni;
        }
    }
}

// ---------------- fused scan_apply + GEMM2 ----------------
// Block = one (batch b, chunk c) = 32 rows. Thread p: load its Bu column
// (32 indep uint loads), run the recurrence in registers seeded from prefix,
// pack x (bf16, same f2bf rounding as before) into swizzled LDS; then the
// block computes out[32][256] = u + gelu( x[32][512] @ W2t^T ).
// x never touches global memory.
__launch_bounds__(256, 2)
__global__ void apply_gemm2_k(const unsigned short* __restrict__ Bu,
                              const float* __restrict__ par,
                              const float* __restrict__ prefix,
                              const unsigned short* __restrict__ W2t,
                              const float* __restrict__ u, float* __restrict__ out) {
    __shared__ __align__(16) unsigned short Xs[32 * 512];     // 32 KB, swizzled
    __shared__ __align__(16) unsigned short Bs[2][256 * 32];  // 32 KB
    const int t = threadIdx.x;
    const int lane = t & 63, w = t >> 6;
    const int c = blockIdx.x, b = blockIdx.y;
    const size_t row0 = (size_t)b * LSEQ + (size_t)c * CHLEN;

    // W2t staging (rule-#21 involution, as GEMM Bs): wave w stages rows 64w..64w+63
    const int srow   = 64 * w + (lane >> 2);
    const int schunk = (lane & 3) ^ ((lane >> 3) & 3);
    const unsigned short* gB = W2t + (size_t)srow * 512 + schunk * 8;
    const int bl0 = (64 * w) * 32;

    // issue tile-0 staging early: latency hides under the recurrence chain
    #pragma unroll
    for (int m = 0; m < 4; m++)
        gload_lds16(gB + m * 16 * 512, &Bs[0][bl0 + m * 16 * 32]);

    // ---------- apply phase: thread p owns complex column p ----------
    {
        const int p = t;
        const unsigned int* q = (const unsigned int*)(Bu + row0 * 512) + p;
        unsigned int vv[32];
        #pragma unroll
        for (int j = 0; j < 32; j++) vv[j] = q[(size_t)j * 256];
        const float2 P = ((const float2*)(prefix + ((size_t)b * NCHUNK + c) * 512))[p];
        const float ar = par[2 * p], ai = par[2 * p + 1];
        float xr = P.x, xi = P.y;
        #pragma unroll
        for (int j = 0; j < 32; j++) {
            float vr = bf2f(vv[j] & 0xFFFFu), vi = bf2f(vv[j] >> 16);
            float nr = fmaf(ar, xr, fmaf(-ai, xi, vr));
            float ni = fmaf(ar, xi, fmaf(ai, xr, vi));
            xr = nr; xi = ni;
            unsigned int pk = (unsigned int)f2bf(xr) | ((unsigned int)f2bf(xi) << 16);
            // Xs[j][.]: 16B-chunk = p>>2, swizzle ^= j&7, word = p&3
            *(unsigned int*)&Xs[j * 512 + ((((p >> 2) ^ (j & 7)) << 3) + (p & 3) * 2)] = pk;
        }
    }

    // ---------- GEMM phase: out cols 64w..64w+63, rows 0..31 ----------
    const int mrow = lane & 15;
    const int rsw  = (mrow >> 1) & 3;
    const int cch  = lane >> 4;
    const int fcol = (cch ^ rsw) * 8;

    f32x4 acc[2][4] = {};
    constexpr int NT = 16;   // K = 512

    __syncthreads();         // Xs complete + Bs tile0 landed

    #pragma unroll
    for (int tt = 0; tt < NT; ++tt) {
        const int cur = tt & 1;
        if (tt + 1 < NT) {
            const int k0 = (tt + 1) * 32;
            #pragma unroll
            for (int m = 0; m < 4; m++)
                gload_lds16(gB + m * 16 * 512 + k0, &Bs[cur ^ 1][bl0 + m * 16 * 32]);
        }
        const int cb = tt * 4;
        bf16x8 fa[2], fb[4];
        #pragma unroll
        for (int i = 0; i < 2; i++) {
            const int r = i * 16 + mrow;
            fa[i] = *(const bf16x8*)&Xs[r * 512 + (((cb + cch) ^ (r & 7)) << 3)];
        }
        #pragma unroll
        for (int j = 0; j < 4; j++)
            fb[j] = *(const bf16x8*)&Bs[cur][(64 * w + j * 16 + mrow) * 32 + fcol];
        #pragma unroll
        for (int i = 0; i < 2; i++)
            #pragma unroll
            for (int j = 0; j < 4; j++)
                acc[i][j] = __builtin_amdgcn_mfma_f32_16x16x32_bf16(fa[i], fb[j], acc[i][j], 0, 0, 0);
        __syncthreads();
    }

    // epilogue: out = u + gelu(acc), fp32
    const int r0 = (lane >> 4) * 4, c0 = lane & 15;
    #pragma unroll
    for (int i = 0; i < 2; i++) {
        #pragma unroll
        for (int r = 0; r < 4; r++) {
            const size_t rowoff = (row0 + i * 16 + r0 + r) * HDIM;
            #pragma unroll
            for (int j = 0; j < 4; j++) {
                const int col = 64 * w + j * 16 + c0;
                float y = acc[i][j][r];
                float z = 0.7978845608f * fmaf(0.044715f * y * y, y, y);
                float e = __expf(2.0f * z);
                float th = 1.0f - 2.0f / (e + 1.0f);
                float g = 0.5f * y * (1.0f + th);
                out[rowoff + col] = u[rowoff + col] + g;
            }
        }
    }
}

extern "C" void kernel_launch(void* const* d_in, const int* in_sizes, int n_in,
                              void* d_out, int out_size, void* d_ws, size_t ws_size,
                              hipStream_t stream) {
    const float* u   = (const float*)d_in[0];
    const float* llr = (const float*)d_in[1];
    const float* lim = (const float*)d_in[2];
    const float* Br  = (const float*)d_in[3];
    const float* Bi  = (const float*)d_in[4];
    const float* Cr  = (const float*)d_in[5];
    const float* Ci  = (const float*)d_in[6];
    const float* ldl = (const float*)d_in[7];
    const float* gam = (const float*)d_in[8];
    const float* bet = (const float*)d_in[9];
    float* out = (float*)d_out;

    float* ws     = (float*)d_ws;
    float* par    = ws;                                     // 2048 floats
    float* last   = ws + 2048;                              // 8*128*512 floats (2 MB)
    float* prefix = last + (size_t)BATCH * NCHUNK * 512;    // 2 MB
    unsigned short* W1t = (unsigned short*)(prefix + (size_t)BATCH * NCHUNK * 512);
    unsigned short* W2t = W1t + 512 * HDIM;                 // [256][512]
    unsigned short* Bu  = W2t + HDIM * 512;                 // [32768][512] bf16

    wpack_k<<<2 * PDIM + 1, HDIM, 0, stream>>>(llr, lim, ldl, Br, Bi, Cr, Ci, W1t, W2t, par);

    // fused LN + GEMM1: Bu = LN(u) @ W1t^T
    ln_gemm1_k<<<dim3(512 / 128, MTOT / 128), 256, 0, stream>>>(u, W1t, Bu, gam, bet);

    scan_reduce_k<<<dim3(NCHUNK / 4, BATCH), 256, 0, stream>>>(Bu, par, last);
    scan_carry_k<<<BATCH, PDIM, 0, stream>>>(last, prefix, par);

    // fused scan_apply + GEMM2: out = u + gelu( x @ W2t^T ), x in LDS only
    apply_gemm2_k<<<dim3(NCHUNK, BATCH), 256, 0, stream>>>(Bu, par, prefix, W2t, u, out);
}